// Round 3
// baseline (664.435 us; speedup 1.0000x reference)
//
#include <hip/hip_runtime.h>
#include <hip/hip_bf16.h>
#include <stdint.h>

#define N_TOK 4096
#define D_ 1024
#define H_ 4096
#define E_ 8
#define NSLOT (N_TOK*2)
#define BM 128
#define BN 128
#define BK 32
#define MAXT 72

typedef __attribute__((ext_vector_type(8))) short short8;
typedef __attribute__((ext_vector_type(4))) float floatx4;
typedef unsigned int u32;

__device__ __forceinline__ unsigned short f2bf(float f){
    union { float f; unsigned int u; } c; c.f = f;
    unsigned int u = c.u;
    unsigned int r = (u + 0x7fffu + ((u >> 16) & 1u)) >> 16;  // RNE
    return (unsigned short)r;
}

__device__ __forceinline__ void async16(const void* g, void* l){
    __builtin_amdgcn_global_load_lds(
        (const __attribute__((address_space(1))) u32*)g,
        (__attribute__((address_space(3))) u32*)l, 16, 0, 0);
}

// ---------------- fp32 -> bf16 weight conversion -----------------------------
__global__ __launch_bounds__(256) void cvt_kernel(
    const float* __restrict__ src, unsigned short* __restrict__ dst, int n4)
{
    int stride = gridDim.x * 256;
    for (int i = blockIdx.x * 256 + threadIdx.x; i < n4; i += stride){
        float4 v = ((const float4*)src)[i];
        ushort4 o; o.x=f2bf(v.x); o.y=f2bf(v.y); o.z=f2bf(v.z); o.w=f2bf(v.w);
        ((ushort4*)dst)[i] = o;
    }
}

// ---------------- Router: fp32 logits, top-2, softmax(2) ---------------------
__global__ __launch_bounds__(256) void router_kernel(
    const float* __restrict__ x, const float* __restrict__ Wr,
    const float* __restrict__ br, int* __restrict__ topIdx,
    float* __restrict__ topGate)
{
    int n = blockIdx.x * 4 + (threadIdx.x >> 6);
    int lane = threadIdx.x & 63;
    const float4* xp = (const float4*)(x + (size_t)n * D_);
    float acc[E_];
#pragma unroll
    for (int e = 0; e < E_; e++) acc[e] = 0.f;
#pragma unroll
    for (int j = 0; j < 4; j++){
        int idx = j * 64 + lane;
        float4 xv = xp[idx];
#pragma unroll
        for (int e = 0; e < E_; e++){
            float4 wv = ((const float4*)(Wr + (size_t)e * D_))[idx];
            acc[e] += xv.x*wv.x + xv.y*wv.y + xv.z*wv.z + xv.w*wv.w;
        }
    }
#pragma unroll
    for (int e = 0; e < E_; e++){
        float v = acc[e];
        for (int off = 32; off > 0; off >>= 1) v += __shfl_xor(v, off, 64);
        acc[e] = v;
    }
    if (lane == 0){
        float best = -1e30f, second = -1e30f; int bi = 0, si = 0;
#pragma unroll
        for (int e = 0; e < E_; e++){
            float v = acc[e] + br[e];
            if (v > best){ second = best; si = bi; best = v; bi = e; }
            else if (v > second){ second = v; si = e; }
        }
        float e1 = __expf(second - best);
        float denom = 1.f + e1;
        topIdx[n*2+0] = bi;  topIdx[n*2+1] = si;
        topGate[n*2+0] = 1.f/denom;  topGate[n*2+1] = e1/denom;
    }
}

__global__ __launch_bounds__(256) void hist_kernel(
    const int* __restrict__ topIdx, int* __restrict__ hdr)
{
    __shared__ int c[E_];
    int t = threadIdx.x;
    if (t < E_) c[t] = 0;
    __syncthreads();
    int e = topIdx[blockIdx.x * 256 + t];
    atomicAdd(&c[e], 1);
    __syncthreads();
    if (t < E_) hdr[256 + blockIdx.x * E_ + t] = c[t];
}

__global__ __launch_bounds__(64) void scan2_kernel(int* __restrict__ hdr)
{
    __shared__ int cnt[32 * E_];
    __shared__ int tot[E_];
    __shared__ int offs[E_ + 1];
    int t = threadIdx.x;
    for (int i = t; i < 32 * E_; i += 64) cnt[i] = hdr[256 + i];
    __syncthreads();
    if (t < E_){
        int s = 0;
        for (int b = 0; b < 32; b++) s += cnt[b * E_ + t];
        tot[t] = s;
    }
    __syncthreads();
    if (t == 0){
        int o = 0;
        for (int e = 0; e < E_; e++){ offs[e] = o; o += tot[e]; }
        offs[E_] = o;
    }
    __syncthreads();
    if (t < E_ + 1) hdr[16 + t] = offs[t];
    if (t < E_){
        int run = offs[t];
        for (int b = 0; b < 32; b++){ hdr[512 + b * E_ + t] = run; run += cnt[b * E_ + t]; }
    }
    if (t == 0){
        int tn = 0;
        for (int e = 0; e < E_; e++){
            int nt = (tot[e] + BM - 1) >> 7;
            for (int i = 0; i < nt; i++){ hdr[32 + tn] = e; hdr[112 + tn] = offs[e] + (i << 7); tn++; }
        }
        for (; tn < MAXT; tn++){ hdr[32 + tn] = -1; hdr[112 + tn] = 0; }
    }
}

__global__ __launch_bounds__(256) void pos_kernel(
    const int* __restrict__ topIdx, const float* __restrict__ topGate,
    const int* __restrict__ hdr, int* __restrict__ posOf,
    int* __restrict__ rowTok, float* __restrict__ rowGate)
{
    __shared__ int c[E_];
    int t = threadIdx.x;
    if (t < E_) c[t] = 0;
    __syncthreads();
    int slot = blockIdx.x * 256 + t;
    int e = topIdx[slot];
    int r = atomicAdd(&c[e], 1);
    int pos = hdr[512 + blockIdx.x * E_ + e] + r;
    posOf[slot] = pos;
    rowTok[pos] = slot >> 1;
    rowGate[pos] = topGate[slot];
}

__global__ __launch_bounds__(256) void copy_kernel(
    const float* __restrict__ x, const int* __restrict__ posOf,
    unsigned short* __restrict__ xg)
{
    int slot = blockIdx.x * 4 + (threadIdx.x >> 6);
    int lane = threadIdx.x & 63;
    int n = slot >> 1;
    int pos = posOf[slot];
    const float4* xp = (const float4*)(x + (size_t)n * D_);
    ushort4* op = (ushort4*)(xg + (size_t)pos * D_);
#pragma unroll
    for (int j = 0; j < 4; j++){
        float4 v = xp[j * 64 + lane];
        ushort4 o; o.x=f2bf(v.x); o.y=f2bf(v.y); o.z=f2bf(v.z); o.w=f2bf(v.w);
        op[j * 64 + lane] = o;
    }
}

// ---------------- Grouped GEMM ----------------------------------------------
// A bf16 [rows][Ktot]. B: bf16 (BF16B) or fp32 weights, K-major rows.
// MODE 1: hout = relu(A@W^T+b) bf16. MODE 2: out[tok] += gate*(A@W^T+b).
// Split-K via blockIdx.z (bias added only by z==0 in MODE 2).
template<int MODE, bool BF16B>
__global__ __launch_bounds__(256) void moe_gemm(
    const unsigned short* __restrict__ A, int Ktot,
    const void* __restrict__ Wbase, size_t wStride,
    const float* __restrict__ biasBase, int biasStride,
    const int* __restrict__ hdr,
    const int* __restrict__ rowTok, const float* __restrict__ rowGate,
    unsigned short* __restrict__ hout, float* __restrict__ out)
{
    // dispatch-order swizzle: by fast within groups of 8 (A + W-slice locality)
    int gid = blockIdx.y * gridDim.x + blockIdx.x;
    int per = gridDim.x * 8;
    int g = gid / per, rr = gid % per;
    int by = g * 8 + (rr & 7);
    int bx = rr >> 3;

    int e = hdr[32 + bx];
    if (e < 0) return;
    int rowBase = hdr[112 + bx];
    int validRows = hdr[16 + e + 1] - rowBase;

    int kChunk = Ktot / gridDim.z;
    int kStart = blockIdx.z * kChunk;

    __shared__ __align__(16) unsigned short As[BM * BK];          // 8 KB
    __shared__ __align__(16) unsigned short BsH[BF16B ? BN * BK : 1];   // 8 KB
    __shared__ __align__(16) float BsF[BF16B ? 1 : BN * BK];            // 16 KB

    const float* biasE = biasBase + (size_t)e * biasStride + by * BN;

    const int tid  = threadIdx.x;
    const int lane = tid & 63, wave = tid >> 6;
    const int wm = wave & 1, wn = wave >> 1;
    const int l16 = lane & 15, quad = lane >> 4;

    floatx4 acc[4][4];
#pragma unroll
    for (int mi = 0; mi < 4; mi++)
#pragma unroll
        for (int ni = 0; ni < 4; ni++)
            acc[mi][ni] = (floatx4){0.f,0.f,0.f,0.f};

    int aS[2], aRow[2], aCol[2];
#pragma unroll
    for (int i = 0; i < 2; i++){
        int s = i * 256 + tid;
        aS[i] = s;
        int r = rowBase + (s >> 2);
        aRow[i] = r < (NSLOT - 1) ? r : (NSLOT - 1);
        aCol[i] = (s & 3) * 8;
    }

    if (BF16B){
        const unsigned short* Wexp = (const unsigned short*)Wbase
            + (size_t)e * wStride + (size_t)(by * BN) * Ktot;
        for (int k0 = kStart; k0 < kStart + kChunk; k0 += BK){
#pragma unroll
            for (int i = 0; i < 2; i++)
                async16(A + (size_t)aRow[i] * Ktot + k0 + aCol[i], (char*)As + aS[i] * 16);
#pragma unroll
            for (int i = 0; i < 2; i++){
                int s = i * 256 + tid;
                async16(Wexp + (size_t)(s >> 2) * Ktot + k0 + (s & 3) * 8,
                        (char*)BsH + s * 16);
            }
            __syncthreads();
            short8 af[4], bfr[4];
#pragma unroll
            for (int mi = 0; mi < 4; mi++)
                af[mi] = *(const short8*)(As + (wm*64 + mi*16 + l16) * BK + quad * 8);
#pragma unroll
            for (int ni = 0; ni < 4; ni++)
                bfr[ni] = *(const short8*)(BsH + (wn*64 + ni*16 + l16) * BK + quad * 8);
#pragma unroll
            for (int mi = 0; mi < 4; mi++)
#pragma unroll
                for (int ni = 0; ni < 4; ni++)
                    acc[mi][ni] = __builtin_amdgcn_mfma_f32_16x16x32_bf16(
                        af[mi], bfr[ni], acc[mi][ni], 0, 0, 0);
            __syncthreads();
        }
    } else {
        const float* Wexp = (const float*)Wbase
            + (size_t)e * wStride + (size_t)(by * BN) * Ktot;
        int bS[4], bRow[4], bCol[4];
#pragma unroll
        for (int i = 0; i < 4; i++){
            int s = i * 256 + tid;
            bS[i] = s;
            int r = s >> 3, c = s & 7;
            bRow[i] = r;
            bCol[i] = (c ^ (r & 7)) * 4;
        }
        for (int k0 = kStart; k0 < kStart + kChunk; k0 += BK){
#pragma unroll
            for (int i = 0; i < 2; i++)
                async16(A + (size_t)aRow[i] * Ktot + k0 + aCol[i], (char*)As + aS[i] * 16);
#pragma unroll
            for (int i = 0; i < 4; i++)
                async16(Wexp + (size_t)bRow[i] * Ktot + k0 + bCol[i], (char*)BsF + bS[i] * 16);
            __syncthreads();
            short8 af[4], bfr[4];
#pragma unroll
            for (int mi = 0; mi < 4; mi++)
                af[mi] = *(const short8*)(As + (wm*64 + mi*16 + l16) * BK + quad * 8);
#pragma unroll
            for (int ni = 0; ni < 4; ni++){
                int n = wn*64 + ni*16 + l16;
                int g0 = (2*quad)     ^ (n & 7);
                int g1 = (2*quad + 1) ^ (n & 7);
                float4 u0 = *(const float4*)(BsF + n * BK + g0 * 4);
                float4 u1 = *(const float4*)(BsF + n * BK + g1 * 4);
                union { short8 s; __hip_bfloat162 h[4]; } u;
                u.h[0] = __float22bfloat162_rn(make_float2(u0.x, u0.y));
                u.h[1] = __float22bfloat162_rn(make_float2(u0.z, u0.w));
                u.h[2] = __float22bfloat162_rn(make_float2(u1.x, u1.y));
                u.h[3] = __float22bfloat162_rn(make_float2(u1.z, u1.w));
                bfr[ni] = u.s;
            }
#pragma unroll
            for (int mi = 0; mi < 4; mi++)
#pragma unroll
                for (int ni = 0; ni < 4; ni++)
                    acc[mi][ni] = __builtin_amdgcn_mfma_f32_16x16x32_bf16(
                        af[mi], bfr[ni], acc[mi][ni], 0, 0, 0);
            __syncthreads();
        }
    }

    bool addB = (MODE == 1) || (blockIdx.z == 0);
#pragma unroll
    for (int mi = 0; mi < 4; mi++){
#pragma unroll
        for (int r = 0; r < 4; r++){
            int rl = wm*64 + mi*16 + quad*4 + r;
            if (rl >= validRows) continue;
            int grow = rowBase + rl;
            int   tok  = 0;
            float gate = 0.f;
            if (MODE == 2){ tok = rowTok[grow]; gate = rowGate[grow]; }
#pragma unroll
            for (int ni = 0; ni < 4; ni++){
                int lcol = wn*64 + ni*16 + l16;
                int gcol = by * BN + lcol;
                float v = acc[mi][ni][r] + (addB ? biasE[lcol] : 0.f);
                if (MODE == 1){
                    v = v > 0.f ? v : 0.f;
                    hout[(size_t)grow * H_ + gcol] = f2bf(v);
                } else {
                    atomicAdd(out + (size_t)tok * D_ + gcol, gate * v);
                }
            }
        }
    }
}

// ---------------- launch -----------------------------------------------------
extern "C" void kernel_launch(void* const* d_in, const int* in_sizes, int n_in,
                              void* d_out, int out_size, void* d_ws, size_t ws_size,
                              hipStream_t stream)
{
    (void)in_sizes; (void)n_in;
    const float* x  = (const float*)d_in[0];
    const float* Wr = (const float*)d_in[1];
    const float* br = (const float*)d_in[2];
    const float* W1 = (const float*)d_in[3];
    const float* b1 = (const float*)d_in[4];
    const float* W2 = (const float*)d_in[5];
    const float* b2 = (const float*)d_in[6];
    float* out = (float*)d_out;

    char* ws = (char*)d_ws;
    int*   hdr     = (int*)ws;
    int*   topIdx  = (int*)  (ws + 4096);
    float* topGate = (float*)(ws + 36864);
    int*   posOf   = (int*)  (ws + 69632);
    int*   rowTok  = (int*)  (ws + 102400);
    float* rowGate = (float*)(ws + 135168);
    unsigned short* xg   = (unsigned short*)(ws + 262144);     // 16.78 MB
    unsigned short* hbuf = (unsigned short*)(ws + 17039360);   // 67.1 MB
    unsigned short* w1b  = (unsigned short*)(ws + 84148224);   // 67.1 MB
    unsigned short* w2b  = (unsigned short*)(ws + 151257088);  // 67.1 MB -> ends 218365952
    const bool full = ws_size >= 218365952ull;

    hipMemsetAsync(d_out, 0, (size_t)out_size * sizeof(float), stream);

    router_kernel<<<N_TOK/4, 256, 0, stream>>>(x, Wr, br, topIdx, topGate);
    hist_kernel<<<32, 256, 0, stream>>>(topIdx, hdr);
    scan2_kernel<<<1, 64, 0, stream>>>(hdr);
    pos_kernel<<<32, 256, 0, stream>>>(topIdx, topGate, hdr, posOf, rowTok, rowGate);
    copy_kernel<<<NSLOT/4, 256, 0, stream>>>(x, posOf, xg);

    if (full){
        cvt_kernel<<<2048, 256, 0, stream>>>(W1, w1b, (E_*H_*D_)/4);
        cvt_kernel<<<2048, 256, 0, stream>>>(W2, w2b, (E_*D_*H_)/4);
        moe_gemm<1,true><<<dim3(MAXT, H_/BN, 1), 256, 0, stream>>>(
            xg, D_, w1b, (size_t)H_ * D_, b1, H_, hdr, rowTok, rowGate, hbuf, nullptr);
        moe_gemm<2,true><<<dim3(MAXT, D_/BN, 2), 256, 0, stream>>>(
            hbuf, H_, w2b, (size_t)D_ * H_, b2, D_, hdr, rowTok, rowGate, nullptr, out);
    } else {
        moe_gemm<1,false><<<dim3(MAXT, H_/BN, 1), 256, 0, stream>>>(
            xg, D_, W1, (size_t)H_ * D_, b1, H_, hdr, rowTok, rowGate, hbuf, nullptr);
        moe_gemm<2,false><<<dim3(MAXT, D_/BN, 2), 256, 0, stream>>>(
            hbuf, H_, W2, (size_t)D_ * H_, b2, D_, hdr, rowTok, rowGate, nullptr, out);
    }
}

// Round 4
// 641.362 us; speedup vs baseline: 1.0360x; 1.0360x over previous
//
#include <hip/hip_runtime.h>
#include <hip/hip_bf16.h>
#include <stdint.h>

#define N_TOK 4096
#define D_ 1024
#define H_ 4096
#define E_ 8
#define NSLOT (N_TOK*2)
#define BM 128
#define BN 128
#define BK 32
#define MAXT 72

typedef __attribute__((ext_vector_type(8))) short short8;
typedef __attribute__((ext_vector_type(4))) float floatx4;
typedef unsigned int u32;

__device__ __forceinline__ unsigned short f2bf(float f){
    union { float f; unsigned int u; } c; c.f = f;
    unsigned int u = c.u;
    unsigned int r = (u + 0x7fffu + ((u >> 16) & 1u)) >> 16;  // RNE
    return (unsigned short)r;
}

__device__ __forceinline__ void async16(const void* g, void* l){
    __builtin_amdgcn_global_load_lds(
        (const __attribute__((address_space(1))) u32*)g,
        (__attribute__((address_space(3))) u32*)l, 16, 0, 0);
}

// ---------------- fp32 -> bf16 weight conversion -----------------------------
__global__ __launch_bounds__(256) void cvt_kernel(
    const float* __restrict__ src, unsigned short* __restrict__ dst, int n4)
{
    int stride = gridDim.x * 256;
    for (int i = blockIdx.x * 256 + threadIdx.x; i < n4; i += stride){
        float4 v = ((const float4*)src)[i];
        ushort4 o; o.x=f2bf(v.x); o.y=f2bf(v.y); o.z=f2bf(v.z); o.w=f2bf(v.w);
        ((ushort4*)dst)[i] = o;
    }
}

// ---------------- Router: fp32 logits, top-2, softmax(2) ---------------------
__global__ __launch_bounds__(256) void router_kernel(
    const float* __restrict__ x, const float* __restrict__ Wr,
    const float* __restrict__ br, int* __restrict__ topIdx,
    float* __restrict__ topGate)
{
    int n = blockIdx.x * 4 + (threadIdx.x >> 6);
    int lane = threadIdx.x & 63;
    const float4* xp = (const float4*)(x + (size_t)n * D_);
    float acc[E_];
#pragma unroll
    for (int e = 0; e < E_; e++) acc[e] = 0.f;
#pragma unroll
    for (int j = 0; j < 4; j++){
        int idx = j * 64 + lane;
        float4 xv = xp[idx];
#pragma unroll
        for (int e = 0; e < E_; e++){
            float4 wv = ((const float4*)(Wr + (size_t)e * D_))[idx];
            acc[e] += xv.x*wv.x + xv.y*wv.y + xv.z*wv.z + xv.w*wv.w;
        }
    }
#pragma unroll
    for (int e = 0; e < E_; e++){
        float v = acc[e];
        for (int off = 32; off > 0; off >>= 1) v += __shfl_xor(v, off, 64);
        acc[e] = v;
    }
    if (lane == 0){
        float best = -1e30f, second = -1e30f; int bi = 0, si = 0;
#pragma unroll
        for (int e = 0; e < E_; e++){
            float v = acc[e] + br[e];
            if (v > best){ second = best; si = bi; best = v; bi = e; }
            else if (v > second){ second = v; si = e; }
        }
        float e1 = __expf(second - best);
        float denom = 1.f + e1;
        topIdx[n*2+0] = bi;  topIdx[n*2+1] = si;
        topGate[n*2+0] = 1.f/denom;  topGate[n*2+1] = e1/denom;
    }
}

__global__ __launch_bounds__(256) void hist_kernel(
    const int* __restrict__ topIdx, int* __restrict__ hdr)
{
    __shared__ int c[E_];
    int t = threadIdx.x;
    if (t < E_) c[t] = 0;
    __syncthreads();
    int e = topIdx[blockIdx.x * 256 + t];
    atomicAdd(&c[e], 1);
    __syncthreads();
    if (t < E_) hdr[256 + blockIdx.x * E_ + t] = c[t];
}

__global__ __launch_bounds__(64) void scan2_kernel(int* __restrict__ hdr)
{
    __shared__ int cnt[32 * E_];
    __shared__ int tot[E_];
    __shared__ int offs[E_ + 1];
    int t = threadIdx.x;
    for (int i = t; i < 32 * E_; i += 64) cnt[i] = hdr[256 + i];
    __syncthreads();
    if (t < E_){
        int s = 0;
        for (int b = 0; b < 32; b++) s += cnt[b * E_ + t];
        tot[t] = s;
    }
    __syncthreads();
    if (t == 0){
        int o = 0;
        for (int e = 0; e < E_; e++){ offs[e] = o; o += tot[e]; }
        offs[E_] = o;
    }
    __syncthreads();
    if (t < E_ + 1) hdr[16 + t] = offs[t];
    if (t < E_){
        int run = offs[t];
        for (int b = 0; b < 32; b++){ hdr[512 + b * E_ + t] = run; run += cnt[b * E_ + t]; }
    }
    if (t == 0){
        int tn = 0;
        for (int e = 0; e < E_; e++){
            int nt = (tot[e] + BM - 1) >> 7;
            for (int i = 0; i < nt; i++){ hdr[32 + tn] = e; hdr[112 + tn] = offs[e] + (i << 7); tn++; }
        }
        for (; tn < MAXT; tn++){ hdr[32 + tn] = -1; hdr[112 + tn] = 0; }
    }
}

__global__ __launch_bounds__(256) void pos_kernel(
    const int* __restrict__ topIdx, const float* __restrict__ topGate,
    const int* __restrict__ hdr, int* __restrict__ posOf,
    int* __restrict__ rowTok, float* __restrict__ rowGate)
{
    __shared__ int c[E_];
    int t = threadIdx.x;
    if (t < E_) c[t] = 0;
    __syncthreads();
    int slot = blockIdx.x * 256 + t;
    int e = topIdx[slot];
    int r = atomicAdd(&c[e], 1);
    int pos = hdr[512 + blockIdx.x * E_ + e] + r;
    posOf[slot] = pos;
    rowTok[pos] = slot >> 1;
    rowGate[pos] = topGate[slot];
}

__global__ __launch_bounds__(256) void copy_kernel(
    const float* __restrict__ x, const int* __restrict__ posOf,
    unsigned short* __restrict__ xg)
{
    int slot = blockIdx.x * 4 + (threadIdx.x >> 6);
    int lane = threadIdx.x & 63;
    int n = slot >> 1;
    int pos = posOf[slot];
    const float4* xp = (const float4*)(x + (size_t)n * D_);
    ushort4* op = (ushort4*)(xg + (size_t)pos * D_);
#pragma unroll
    for (int j = 0; j < 4; j++){
        float4 v = xp[j * 64 + lane];
        ushort4 o; o.x=f2bf(v.x); o.y=f2bf(v.y); o.z=f2bf(v.z); o.w=f2bf(v.w);
        op[j * 64 + lane] = o;
    }
}

// ---------------- Grouped GEMM ----------------------------------------------
// A bf16 [rows][Ktot]. B: bf16 (BF16B) or fp32 weights, K-major rows.
// MODE 1: hout = relu(A@W^T+b) bf16. MODE 2: out[tok] += gate*(A@W^T+b).
// BF16B path: double-buffered LDS (1 barrier/iter) + XOR granule swizzle.
template<int MODE, bool BF16B>
__global__ __launch_bounds__(256) void moe_gemm(
    const unsigned short* __restrict__ A, int Ktot,
    const void* __restrict__ Wbase, size_t wStride,
    const float* __restrict__ biasBase, int biasStride,
    const int* __restrict__ hdr,
    const int* __restrict__ rowTok, const float* __restrict__ rowGate,
    unsigned short* __restrict__ hout, float* __restrict__ out)
{
    // dispatch-order swizzle: by fast within groups of 8 (A + W-slice locality)
    int gid = blockIdx.y * gridDim.x + blockIdx.x;
    int per = gridDim.x * 8;
    int g = gid / per, rr = gid % per;
    int by = g * 8 + (rr & 7);
    int bx = rr >> 3;

    int e = hdr[32 + bx];
    if (e < 0) return;
    int rowBase = hdr[112 + bx];
    int validRows = hdr[16 + e + 1] - rowBase;

    int kChunk = Ktot / gridDim.z;
    int kStart = blockIdx.z * kChunk;

    __shared__ __align__(16) unsigned short As[2][BM * BK];                  // 16 KB
    __shared__ __align__(16) unsigned short BsH[BF16B ? 2 * BN * BK : 1];    // 16 KB
    __shared__ __align__(16) float BsF[BF16B ? 1 : BN * BK];                 // fp32 fallback

    const float* biasE = biasBase + (size_t)e * biasStride + by * BN;

    const int tid  = threadIdx.x;
    const int lane = tid & 63, wave = tid >> 6;
    const int wm = wave & 1, wn = wave >> 1;
    const int l16 = lane & 15, quad = lane >> 4;

    floatx4 acc[4][4];
#pragma unroll
    for (int mi = 0; mi < 4; mi++)
#pragma unroll
        for (int ni = 0; ni < 4; ni++)
            acc[mi][ni] = (floatx4){0.f,0.f,0.f,0.f};

    if (BF16B){
        const unsigned short* Wexp = (const unsigned short*)Wbase
            + (size_t)e * wStride + (size_t)(by * BN) * Ktot;

        // per-thread staging descriptors: storage slot s -> swizzled src granule
        size_t aOff[2], bOff[2];
        int    lOff[2];
#pragma unroll
        for (int i = 0; i < 2; i++){
            int s = i * 256 + tid;
            int r = s >> 2, gst = s & 3;
            int gsrc = gst ^ ((r >> 1) & 3);
            int ar = rowBase + r;
            ar = ar < (NSLOT - 1) ? ar : (NSLOT - 1);  // clamp; junk masked in epilogue
            aOff[i] = (size_t)ar * Ktot + gsrc * 8;
            bOff[i] = (size_t)r  * Ktot + gsrc * 8;
            lOff[i] = s * 16;
        }

        // prologue: tile 0 -> buffer 0
#pragma unroll
        for (int i = 0; i < 2; i++){
            async16(A    + aOff[i] + kStart, (char*)As[0]  + lOff[i]);
            async16(Wexp + bOff[i] + kStart, (char*)BsH    + lOff[i]);
        }

        int nIter = kChunk / BK;
        for (int it = 0; it < nIter; it++){
            __syncthreads();                       // buffer p ready (vmcnt drain)
            int p = it & 1;
            if (it + 1 < nIter){
                int kn = kStart + (it + 1) * BK;
#pragma unroll
                for (int i = 0; i < 2; i++){
                    async16(A    + aOff[i] + kn, (char*)As[p ^ 1] + lOff[i]);
                    async16(Wexp + bOff[i] + kn, (char*)BsH + (p ^ 1) * (BN * BK * 2) + lOff[i]);
                }
            }
            short8 af[4], bfr[4];
#pragma unroll
            for (int mi = 0; mi < 4; mi++){
                int r = wm*64 + mi*16 + l16;
                int gq = quad ^ ((r >> 1) & 3);
                af[mi] = *(const short8*)(As[p] + r * BK + gq * 8);
            }
#pragma unroll
            for (int ni = 0; ni < 4; ni++){
                int n = wn*64 + ni*16 + l16;
                int gq = quad ^ ((n >> 1) & 3);
                bfr[ni] = *(const short8*)(BsH + p * (BN * BK) + n * BK + gq * 8);
            }
#pragma unroll
            for (int mi = 0; mi < 4; mi++)
#pragma unroll
                for (int ni = 0; ni < 4; ni++)
                    acc[mi][ni] = __builtin_amdgcn_mfma_f32_16x16x32_bf16(
                        af[mi], bfr[ni], acc[mi][ni], 0, 0, 0);
        }
    } else {
        // fp32-weight fallback (single-buffer, known-correct)
        const float* Wexp = (const float*)Wbase
            + (size_t)e * wStride + (size_t)(by * BN) * Ktot;
        int aS[2], aRow[2], aCol[2];
#pragma unroll
        for (int i = 0; i < 2; i++){
            int s = i * 256 + tid;
            aS[i] = s;
            int r = rowBase + (s >> 2);
            aRow[i] = r < (NSLOT - 1) ? r : (NSLOT - 1);
            aCol[i] = (s & 3) * 8;
        }
        int bS[4], bRow[4], bCol[4];
#pragma unroll
        for (int i = 0; i < 4; i++){
            int s = i * 256 + tid;
            bS[i] = s;
            int r = s >> 3, c = s & 7;
            bRow[i] = r;
            bCol[i] = (c ^ (r & 7)) * 4;
        }
        for (int k0 = kStart; k0 < kStart + kChunk; k0 += BK){
#pragma unroll
            for (int i = 0; i < 2; i++)
                async16(A + (size_t)aRow[i] * Ktot + k0 + aCol[i], (char*)As[0] + aS[i] * 16);
#pragma unroll
            for (int i = 0; i < 4; i++)
                async16(Wexp + (size_t)bRow[i] * Ktot + k0 + bCol[i], (char*)BsF + bS[i] * 16);
            __syncthreads();
            short8 af[4], bfr[4];
#pragma unroll
            for (int mi = 0; mi < 4; mi++)
                af[mi] = *(const short8*)(As[0] + (wm*64 + mi*16 + l16) * BK + quad * 8);
#pragma unroll
            for (int ni = 0; ni < 4; ni++){
                int n = wn*64 + ni*16 + l16;
                int g0 = (2*quad)     ^ (n & 7);
                int g1 = (2*quad + 1) ^ (n & 7);
                float4 u0 = *(const float4*)(BsF + n * BK + g0 * 4);
                float4 u1 = *(const float4*)(BsF + n * BK + g1 * 4);
                union { short8 s; __hip_bfloat162 h[4]; } u;
                u.h[0] = __float22bfloat162_rn(make_float2(u0.x, u0.y));
                u.h[1] = __float22bfloat162_rn(make_float2(u0.z, u0.w));
                u.h[2] = __float22bfloat162_rn(make_float2(u1.x, u1.y));
                u.h[3] = __float22bfloat162_rn(make_float2(u1.z, u1.w));
                bfr[ni] = u.s;
            }
#pragma unroll
            for (int mi = 0; mi < 4; mi++)
#pragma unroll
                for (int ni = 0; ni < 4; ni++)
                    acc[mi][ni] = __builtin_amdgcn_mfma_f32_16x16x32_bf16(
                        af[mi], bfr[ni], acc[mi][ni], 0, 0, 0);
            __syncthreads();
        }
    }

    bool addB = (MODE == 1) || (blockIdx.z == 0);
#pragma unroll
    for (int mi = 0; mi < 4; mi++){
#pragma unroll
        for (int r = 0; r < 4; r++){
            int rl = wm*64 + mi*16 + quad*4 + r;
            if (rl >= validRows) continue;
            int grow = rowBase + rl;
            int   tok  = 0;
            float gate = 0.f;
            if (MODE == 2){ tok = rowTok[grow]; gate = rowGate[grow]; }
#pragma unroll
            for (int ni = 0; ni < 4; ni++){
                int lcol = wn*64 + ni*16 + l16;
                int gcol = by * BN + lcol;
                float v = acc[mi][ni][r] + (addB ? biasE[lcol] : 0.f);
                if (MODE == 1){
                    v = v > 0.f ? v : 0.f;
                    hout[(size_t)grow * H_ + gcol] = f2bf(v);
                } else {
                    atomicAdd(out + (size_t)tok * D_ + gcol, gate * v);
                }
            }
        }
    }
}

// ---------------- launch -----------------------------------------------------
extern "C" void kernel_launch(void* const* d_in, const int* in_sizes, int n_in,
                              void* d_out, int out_size, void* d_ws, size_t ws_size,
                              hipStream_t stream)
{
    (void)in_sizes; (void)n_in;
    const float* x  = (const float*)d_in[0];
    const float* Wr = (const float*)d_in[1];
    const float* br = (const float*)d_in[2];
    const float* W1 = (const float*)d_in[3];
    const float* b1 = (const float*)d_in[4];
    const float* W2 = (const float*)d_in[5];
    const float* b2 = (const float*)d_in[6];
    float* out = (float*)d_out;

    char* ws = (char*)d_ws;
    int*   hdr     = (int*)ws;
    int*   topIdx  = (int*)  (ws + 4096);
    float* topGate = (float*)(ws + 36864);
    int*   posOf   = (int*)  (ws + 69632);
    int*   rowTok  = (int*)  (ws + 102400);
    float* rowGate = (float*)(ws + 135168);
    unsigned short* xg   = (unsigned short*)(ws + 262144);     // 16.78 MB
    unsigned short* hbuf = (unsigned short*)(ws + 17039360);   // 67.1 MB
    unsigned short* w1b  = (unsigned short*)(ws + 84148224);   // 67.1 MB
    unsigned short* w2b  = (unsigned short*)(ws + 151257088);  // 67.1 MB -> ends 218365952
    const bool full = ws_size >= 218365952ull;

    hipMemsetAsync(d_out, 0, (size_t)out_size * sizeof(float), stream);

    router_kernel<<<N_TOK/4, 256, 0, stream>>>(x, Wr, br, topIdx, topGate);
    hist_kernel<<<32, 256, 0, stream>>>(topIdx, hdr);
    scan2_kernel<<<1, 64, 0, stream>>>(hdr);
    pos_kernel<<<32, 256, 0, stream>>>(topIdx, topGate, hdr, posOf, rowTok, rowGate);
    copy_kernel<<<NSLOT/4, 256, 0, stream>>>(x, posOf, xg);

    if (full){
        cvt_kernel<<<2048, 256, 0, stream>>>(W1, w1b, (E_*H_*D_)/4);
        cvt_kernel<<<2048, 256, 0, stream>>>(W2, w2b, (E_*D_*H_)/4);
        moe_gemm<1,true><<<dim3(MAXT, H_/BN, 1), 256, 0, stream>>>(
            xg, D_, w1b, (size_t)H_ * D_, b1, H_, hdr, rowTok, rowGate, hbuf, nullptr);
        moe_gemm<2,true><<<dim3(MAXT, D_/BN, 2), 256, 0, stream>>>(
            hbuf, H_, w2b, (size_t)D_ * H_, b2, D_, hdr, rowTok, rowGate, nullptr, out);
    } else {
        moe_gemm<1,false><<<dim3(MAXT, H_/BN, 1), 256, 0, stream>>>(
            xg, D_, W1, (size_t)H_ * D_, b1, H_, hdr, rowTok, rowGate, hbuf, nullptr);
        moe_gemm<2,false><<<dim3(MAXT, D_/BN, 2), 256, 0, stream>>>(
            hbuf, H_, W2, (size_t)D_ * H_, b2, D_, hdr, rowTok, rowGate, nullptr, out);
    }
}